// Round 1
// baseline (2313.864 us; speedup 1.0000x reference)
//
#include <hip/hip_runtime.h>

#define NN 50000
#define NE 800000
// D=128, H=8, HD=16, channel = h*16+hd

typedef __attribute__((ext_vector_type(8))) short short8;
typedef __attribute__((ext_vector_type(4))) float floatx4;

__device__ __forceinline__ float bf2f(unsigned short u){
  union { unsigned int i; float f; } x; x.i = ((unsigned int)u) << 16; return x.f;
}
__device__ __forceinline__ unsigned short f2bf(float f){
  union { float f; unsigned int i; } x; x.f = f;
  unsigned int r = x.i + 0x7fffu + ((x.i >> 16) & 1u);   // RNE
  return (unsigned short)(r >> 16);
}
__device__ __forceinline__ short8 zero8(){
  short8 z;
#pragma unroll
  for (int j=0;j<8;++j) z[j]=0;
  return z;
}
__device__ __forceinline__ floatx4 zf4(){
  floatx4 z; z[0]=0.f; z[1]=0.f; z[2]=0.f; z[3]=0.f; return z;
}
__device__ __forceinline__ short8 a_from_f32(const float* p){
  float4 u = *(const float4*)(p);
  float4 v = *(const float4*)(p+4);
  short8 r;
  r[0]=(short)f2bf(u.x); r[1]=(short)f2bf(u.y); r[2]=(short)f2bf(u.z); r[3]=(short)f2bf(u.w);
  r[4]=(short)f2bf(v.x); r[5]=(short)f2bf(v.y); r[6]=(short)f2bf(v.z); r[7]=(short)f2bf(v.w);
  return r;
}
#define MFMA16(a,b,c) __builtin_amdgcn_mfma_f32_16x16x32_bf16((a),(b),(c),0,0,0)

// ---------------------------------------------------------------- zero
__global__ void k_zero(float* __restrict__ p, long n){
  long i = (long)blockIdx.x*blockDim.x + threadIdx.x;
  if (i < n) p[i] = 0.f;
}

// ---------------------------------------------------------------- weight swizzle to MFMA B-frag order
// layout per matrix: frag f = (ks*(Nc/16)+ct)*64+lane holds B[k=ks*32+(lane>>4)*8+j][n=ct*16+(lane&15)], j=0..7
__global__ void k_swizzle(const float* __restrict__ wq, const float* __restrict__ wk,
                          const float* __restrict__ wv, const float* __restrict__ we,
                          const float* __restrict__ oh, const float* __restrict__ oe,
                          const float* __restrict__ f1h, const float* __restrict__ f2h,
                          const float* __restrict__ f1e, const float* __restrict__ f2e,
                          unsigned short* __restrict__ dst)
{
  int t = blockIdx.x*256 + threadIdx.x;
  if (t >= 229376) return;
  const float* src; int Nc, base, local;
  if (t < 98304){
    int m = t >> 14; local = t & 16383; base = m << 14; Nc = 128;
    src = (m==0)?wq:(m==1)?wk:(m==2)?wv:(m==3)?we:(m==4)?oh:oe;
  } else {
    int u = t - 98304; int mm = u >> 15; local = u & 32767; base = 98304 + (mm<<15);
    Nc = (mm==0||mm==2) ? 256 : 128;
    src = (mm==0)?f1h:(mm==1)?f2h:(mm==2)?f1e:f2e;
  }
  int j = local & 7, f = local >> 3;
  int lane = f & 63, g = f >> 6;
  int nct = Nc >> 4;
  int ct = g % nct, ks = g / nct;
  int k = ks*32 + ((lane>>4)<<3) + j;
  int n = ct*16 + (lane & 15);
  dst[base + local] = f2bf(src[k*Nc + n]);
}

// ---------------------------------------------------------------- QKV projections (bf16 out)
__global__ __launch_bounds__(256) void k_qkv(const float* __restrict__ h,
                                             const unsigned short* __restrict__ wswz,
                                             unsigned short* __restrict__ Qb,
                                             unsigned short* __restrict__ Kb,
                                             unsigned short* __restrict__ Vb)
{
  const int m = blockIdx.y;
  const int r0 = blockIdx.x * 64;
  const int lane = threadIdx.x & 63, wv = threadIdx.x >> 6;
  const int quad = lane >> 4, lm = lane & 15;
  const short8* B = (const short8*)(wswz + m*16384);
  floatx4 acc[8];
#pragma unroll
  for (int ct=0; ct<8; ++ct) acc[ct] = zf4();
  const int ra = r0 + wv*16 + lm;
  const bool va = ra < NN;
  const float* arow = h + (long)ra*128;
#pragma unroll
  for (int ks=0; ks<4; ++ks){
    short8 a = va ? a_from_f32(arow + ks*32 + quad*8) : zero8();
    const short8* bp = B + (ks*8)*64 + lane;
#pragma unroll
    for (int ct=0; ct<8; ++ct) acc[ct] = MFMA16(a, bp[ct*64], acc[ct]);
  }
  unsigned short* out = (m==0)?Qb:((m==1)?Kb:Vb);
  const int rc = r0 + wv*16 + quad*4;
#pragma unroll
  for (int ct=0; ct<8; ++ct){
    const int c = ct*16 + lm;
#pragma unroll
    for (int i=0;i<4;++i){
      const int r = rc + i;
      if (r < NN) out[(long)r*128 + c] = f2bf(acc[ct][i]);
    }
  }
}

// ---------------------------------------------------------------- fused: score -> (softmax atomics) -> e1_pre
__global__ __launch_bounds__(256) void k_score_e1(
    const float* __restrict__ e, const int* __restrict__ src, const int* __restrict__ dst,
    const unsigned short* __restrict__ Qb, const unsigned short* __restrict__ Kb,
    const unsigned short* __restrict__ Vb,
    const unsigned short* __restrict__ WeS, const unsigned short* __restrict__ OeS,
    const float* __restrict__ Oe_b,
    float* __restrict__ ssum, float* __restrict__ wVnum,
    unsigned short* __restrict__ e1pre, float* __restrict__ statacc)
{
  __shared__ __align__(16) unsigned short T[64][136];
  __shared__ float dotl[64][8];
  __shared__ int srcl[64], dstl[64];
  __shared__ float s_sum[128], s_sq[128];
  const int tid = threadIdx.x;
  const long e0 = (long)blockIdx.x * 64;
  if (tid < 64){ srcl[tid] = src[e0 + tid]; dstl[tid] = dst[e0 + tid]; }
  if (tid >= 128 && tid < 256){ s_sum[tid-128] = 0.f; s_sq[tid-128] = 0.f; }
  __syncthreads();
  // per-(edge,head) dot products <K[src],Q[dst]>/sqrt(HD)
#pragma unroll
  for (int rep=0; rep<2; ++rep){
    int ii = rep*256 + tid;
    int r = ii >> 3, hh = ii & 7;
    const unsigned short* kp = Kb + (long)srcl[r]*128 + hh*16;
    const unsigned short* qp = Qb + (long)dstl[r]*128 + hh*16;
    union { uint4 v; unsigned short u[8]; } k0, k1, q0, q1;
    k0.v = *(const uint4*)kp; k1.v = *(const uint4*)(kp+8);
    q0.v = *(const uint4*)qp; q1.v = *(const uint4*)(qp+8);
    float d = 0.f;
#pragma unroll
    for (int j=0;j<8;++j) d += bf2f(k0.u[j])*bf2f(q0.u[j]);
#pragma unroll
    for (int j=0;j<8;++j) d += bf2f(k1.u[j])*bf2f(q1.u[j]);
    dotl[r][hh] = d * 0.25f;
  }
  const int lane = tid & 63, wv = tid >> 6;
  const int quad = lane >> 4, lm = lane & 15;
  // GEMM1: pe = e @ We
  floatx4 acc[8];
#pragma unroll
  for (int ct=0; ct<8; ++ct) acc[ct] = zf4();
  {
    const float* arow = e + (e0 + wv*16 + lm) * 128;
#pragma unroll
    for (int ks=0; ks<4; ++ks){
      short8 a = a_from_f32(arow + ks*32 + quad*8);
      const short8* bp = (const short8*)WeS + (ks*8)*64 + lane;
#pragma unroll
      for (int ct=0; ct<8; ++ct) acc[ct] = MFMA16(a, bp[ct*64], acc[ct]);
    }
  }
  __syncthreads();   // dotl ready
  // score = pe + dot ; stash to LDS (A-layout for GEMM2); softmax atomics
  const int rc = wv*16 + quad*4;
#pragma unroll
  for (int ct=0; ct<8; ++ct){
    const int c = ct*16 + lm;
#pragma unroll
    for (int i=0;i<4;++i){
      const int r = rc + i;
      float s = acc[ct][i] + dotl[r][ct];
      T[r][c] = f2bf(s);
      float ex = __expf(s);          // no max-shift needed: |s| ~ O(1)
      long dd = dstl[r], ss = srcl[r];
      atomicAdd(ssum + dd*128 + c, ex);
      atomicAdd(wVnum + dd*128 + c, ex * bf2f(Vb[ss*128 + c]));
    }
  }
  __syncthreads();
  // GEMM2: e1 = score @ Oe_w
  floatx4 accO[8];
#pragma unroll
  for (int ct=0; ct<8; ++ct) accO[ct] = zf4();
#pragma unroll
  for (int ks=0; ks<4; ++ks){
    short8 a = *(const short8*)&T[wv*16 + lm][ks*32 + quad*8];
    const short8* bp = (const short8*)OeS + (ks*8)*64 + lane;
#pragma unroll
    for (int ct=0; ct<8; ++ct) accO[ct] = MFMA16(a, bp[ct*64], accO[ct]);
  }
  // epilogue: + bias + residual e ; bn1e stats
#pragma unroll
  for (int ct=0; ct<8; ++ct){
    const int c = ct*16 + lm;
    const float bias = Oe_b[c];
    float s = 0.f, q = 0.f;
#pragma unroll
    for (int i=0;i<4;++i){
      long er = e0 + rc + i;
      float val = accO[ct][i] + bias + e[er*128 + c];
      e1pre[er*128 + c] = f2bf(val);
      s += val; q += val*val;
    }
    s += __shfl_xor(s,16,64); s += __shfl_xor(s,32,64);
    q += __shfl_xor(q,16,64); q += __shfl_xor(q,32,64);
    if (quad == 0){ atomicAdd(&s_sum[c], s); atomicAdd(&s_sq[c], q); }
  }
  __syncthreads();
  if (tid < 128){ atomicAdd(statacc + 256 + tid, s_sum[tid]); atomicAdd(statacc + 384 + tid, s_sq[tid]); }
}

// ---------------------------------------------------------------- h1_pre = h + (wVnum/ssum) @ Oh_w + b ; bn1h stats
__global__ __launch_bounds__(256) void k_h1(
    const float* __restrict__ h, const float* __restrict__ ssum, const float* __restrict__ wVnum,
    const unsigned short* __restrict__ OhS, const float* __restrict__ Oh_b,
    unsigned short* __restrict__ h1pre, float* __restrict__ statacc)
{
  __shared__ float s_sum[128], s_sq[128];
  const int tid = threadIdx.x;
  if (tid < 128){ s_sum[tid]=0.f; s_sq[tid]=0.f; }
  __syncthreads();
  const int lane = tid & 63, wv = tid >> 6;
  const int quad = lane >> 4, lm = lane & 15;
  const int r0 = blockIdx.x * 64;
  const int ra = r0 + wv*16 + lm;
  const bool va = ra < NN;
  floatx4 acc[8];
#pragma unroll
  for (int ct=0; ct<8; ++ct) acc[ct] = zf4();
#pragma unroll
  for (int ks=0; ks<4; ++ks){
    short8 a;
    if (va){
      const float* np = wVnum + (long)ra*128 + ks*32 + quad*8;
      const float* dp = ssum  + (long)ra*128 + ks*32 + quad*8;
      float4 n0=*(const float4*)np, n1=*(const float4*)(np+4);
      float4 d0=*(const float4*)dp, d1=*(const float4*)(dp+4);
      a[0]=(short)f2bf(d0.x>0.f ? n0.x/d0.x : 0.f);
      a[1]=(short)f2bf(d0.y>0.f ? n0.y/d0.y : 0.f);
      a[2]=(short)f2bf(d0.z>0.f ? n0.z/d0.z : 0.f);
      a[3]=(short)f2bf(d0.w>0.f ? n0.w/d0.w : 0.f);
      a[4]=(short)f2bf(d1.x>0.f ? n1.x/d1.x : 0.f);
      a[5]=(short)f2bf(d1.y>0.f ? n1.y/d1.y : 0.f);
      a[6]=(short)f2bf(d1.z>0.f ? n1.z/d1.z : 0.f);
      a[7]=(short)f2bf(d1.w>0.f ? n1.w/d1.w : 0.f);
    } else a = zero8();
    const short8* bp = (const short8*)OhS + (ks*8)*64 + lane;
#pragma unroll
    for (int ct=0; ct<8; ++ct) acc[ct] = MFMA16(a, bp[ct*64], acc[ct]);
  }
  const int rc = r0 + wv*16 + quad*4;
#pragma unroll
  for (int ct=0; ct<8; ++ct){
    const int c = ct*16 + lm;
    const float bias = Oh_b[c];
    float s = 0.f, q = 0.f;
#pragma unroll
    for (int i=0;i<4;++i){
      const int r = rc + i;
      if (r < NN){
        float val = acc[ct][i] + bias + h[(long)r*128 + c];
        h1pre[(long)r*128 + c] = f2bf(val);
        s += val; q += val*val;
      }
    }
    s += __shfl_xor(s,16,64); s += __shfl_xor(s,32,64);
    q += __shfl_xor(q,16,64); q += __shfl_xor(q,32,64);
    if (quad == 0){ atomicAdd(&s_sum[c], s); atomicAdd(&s_sq[c], q); }
  }
  __syncthreads();
  if (tid < 128){ atomicAdd(statacc + tid, s_sum[tid]); atomicAdd(statacc + 128 + tid, s_sq[tid]); }
}

// ---------------------------------------------------------------- finalize BN pair -> scale/shift
__global__ void k_bnfin(const float* __restrict__ acc, float* __restrict__ fin,
                        const float* __restrict__ g_h, const float* __restrict__ b_h,
                        const float* __restrict__ g_e, const float* __restrict__ b_e,
                        float Mh, float Me)
{
  const int tid = threadIdx.x;
  const int which = tid >> 7, ch = tid & 127;
  const float M = which ? Me : Mh;
  const float* g = which ? g_e : g_h;
  const float* b = which ? b_e : b_h;
  float mu = acc[which*256 + ch] / M;
  float var = acc[which*256 + 128 + ch] / M - mu*mu;
  float sc = g[ch] * rsqrtf(var + 1e-5f);
  fin[which*256 + ch] = sc;
  fin[which*256 + 128 + ch] = b[ch] - mu*sc;
}

// ---------------------------------------------------------------- fused BN-apply + FFN + residual -> pre-BN2 (fp32 into d_out)
__global__ __launch_bounds__(256) void k_ffn(
    const unsigned short* __restrict__ inb, int M,
    const unsigned short* __restrict__ W1S, const float* __restrict__ b1,
    const unsigned short* __restrict__ W2S, const float* __restrict__ b2,
    const float* __restrict__ scale, const float* __restrict__ shift,
    float* __restrict__ out, float* __restrict__ stat_s, float* __restrict__ stat_q)
{
  __shared__ __align__(16) unsigned short T[64][136];
  __shared__ float s_sum[128], s_sq[128];
  const int tid = threadIdx.x;
  if (tid < 128){ s_sum[tid]=0.f; s_sq[tid]=0.f; }
  const int lane = tid & 63, wv = tid >> 6;
  const int quad = lane >> 4, lm = lane & 15;
  const int r0 = blockIdx.x * 64;
  const int ra = r0 + wv*16 + lm;
  const bool va = ra < M;
  short8 af[4];
  if (va){
    const short8* inrow = (const short8*)(inb + (long)ra*128);
#pragma unroll
    for (int ks=0; ks<4; ++ks){
      short8 x = inrow[ks*4 + quad];
      int kc = ks*32 + quad*8;
      float4 s0 = *(const float4*)(scale+kc), s1 = *(const float4*)(scale+kc+4);
      float4 t0 = *(const float4*)(shift+kc), t1 = *(const float4*)(shift+kc+4);
      short8 a;
      a[0]=(short)f2bf(s0.x*bf2f((unsigned short)x[0])+t0.x);
      a[1]=(short)f2bf(s0.y*bf2f((unsigned short)x[1])+t0.y);
      a[2]=(short)f2bf(s0.z*bf2f((unsigned short)x[2])+t0.z);
      a[3]=(short)f2bf(s0.w*bf2f((unsigned short)x[3])+t0.w);
      a[4]=(short)f2bf(s1.x*bf2f((unsigned short)x[4])+t1.x);
      a[5]=(short)f2bf(s1.y*bf2f((unsigned short)x[5])+t1.y);
      a[6]=(short)f2bf(s1.z*bf2f((unsigned short)x[6])+t1.z);
      a[7]=(short)f2bf(s1.w*bf2f((unsigned short)x[7])+t1.w);
      af[ks] = a;
    }
  } else {
#pragma unroll
    for (int ks=0;ks<4;++ks) af[ks] = zero8();
  }
  floatx4 accO[8];
#pragma unroll
  for (int ct=0; ct<8; ++ct) accO[ct] = zf4();
  const int rc = wv*16 + quad*4;
#pragma unroll
  for (int half=0; half<2; ++half){
    floatx4 accT[8];
#pragma unroll
    for (int ct=0; ct<8; ++ct) accT[ct] = zf4();
#pragma unroll
    for (int ks=0; ks<4; ++ks){
      const short8* bp = (const short8*)W1S + ((ks*16 + half*8)*64) + lane;
#pragma unroll
      for (int ct=0; ct<8; ++ct) accT[ct] = MFMA16(af[ks], bp[ct*64], accT[ct]);
    }
#pragma unroll
    for (int ct=0; ct<8; ++ct){
      const int tc = ct*16 + lm;
      const float bb = b1[half*128 + tc];
#pragma unroll
      for (int i=0;i<4;++i){
        float t = accT[ct][i] + bb;
        T[rc + i][tc] = f2bf(fmaxf(t, 0.f));
      }
    }
    __syncthreads();
#pragma unroll
    for (int ks=0; ks<4; ++ks){
      short8 a = *(const short8*)&T[wv*16 + lm][ks*32 + quad*8];
      const short8* bp = (const short8*)W2S + (((half*4 + ks)*8)*64) + lane;
#pragma unroll
      for (int ct=0; ct<8; ++ct) accO[ct] = MFMA16(a, bp[ct*64], accO[ct]);
    }
    __syncthreads();
  }
#pragma unroll
  for (int ct=0; ct<8; ++ct){
    const int c = ct*16 + lm;
    const float bb = b2[c];
    const float sc = scale[c], sh = shift[c];
    float s = 0.f, q = 0.f;
#pragma unroll
    for (int i=0;i<4;++i){
      const int r = r0 + rc + i;
      if (r < M){
        float xres = sc*bf2f(inb[(long)r*128 + c]) + sh;
        float val = accO[ct][i] + bb + xres;
        out[(long)r*128 + c] = val;
        s += val; q += val*val;
      }
    }
    s += __shfl_xor(s,16,64); s += __shfl_xor(s,32,64);
    q += __shfl_xor(q,16,64); q += __shfl_xor(q,32,64);
    if (quad == 0){ atomicAdd(&s_sum[c], s); atomicAdd(&s_sq[c], q); }
  }
  __syncthreads();
  if (tid < 128){ atomicAdd(stat_s + tid, s_sum[tid]); atomicAdd(stat_q + tid, s_sq[tid]); }
}

// ---------------------------------------------------------------- in-place BN2 apply on d_out
__global__ __launch_bounds__(256) void k_final(float* __restrict__ out, const float* __restrict__ fin){
  const long idx = (long)blockIdx.x*256 + threadIdx.x;    // one float4 each
  const long NH4 = (long)NN*128/4;
  const long TOT4 = ((long)NN + (long)NE)*128/4;
  if (idx >= TOT4) return;
  const float* sc; const float* sh; long rel;
  if (idx < NH4){ sc = fin+512; sh = fin+640; rel = idx; }
  else { sc = fin+768; sh = fin+896; rel = idx - NH4; }
  const int c = (int)((rel*4) & 127);
  float4 v = ((float4*)out)[idx];
  float4 s = *(const float4*)(sc + c);
  float4 t = *(const float4*)(sh + c);
  v.x = fmaf(s.x, v.x, t.x);
  v.y = fmaf(s.y, v.y, t.y);
  v.z = fmaf(s.z, v.z, t.z);
  v.w = fmaf(s.w, v.w, t.w);
  ((float4*)out)[idx] = v;
}

extern "C" void kernel_launch(void* const* d_in, const int* in_sizes, int n_in,
                              void* d_out, int out_size, void* d_ws, size_t ws_size,
                              hipStream_t stream)
{
  const float* h   = (const float*)d_in[0];
  const float* e   = (const float*)d_in[1];
  const int* srcI  = (const int*)d_in[2];
  const int* dstI  = (const int*)d_in[3];
  const float* Wq  = (const float*)d_in[4];
  const float* Wk  = (const float*)d_in[5];
  const float* Wv  = (const float*)d_in[6];
  const float* We  = (const float*)d_in[7];
  const float* Ohw = (const float*)d_in[8];
  const float* Ohb = (const float*)d_in[9];
  const float* Oew = (const float*)d_in[10];
  const float* Oeb = (const float*)d_in[11];
  const float* g1h = (const float*)d_in[12]; const float* b1h = (const float*)d_in[13];
  const float* g1e = (const float*)d_in[14]; const float* b1e = (const float*)d_in[15];
  const float* g2h = (const float*)d_in[16]; const float* b2h = (const float*)d_in[17];
  const float* g2e = (const float*)d_in[18]; const float* b2e = (const float*)d_in[19];
  const float* f1hw= (const float*)d_in[20]; const float* f1hb= (const float*)d_in[21];
  const float* f2hw= (const float*)d_in[22]; const float* f2hb= (const float*)d_in[23];
  const float* f1ew= (const float*)d_in[24]; const float* f1eb= (const float*)d_in[25];
  const float* f2ew= (const float*)d_in[26]; const float* f2eb= (const float*)d_in[27];
  (void)in_sizes; (void)n_in; (void)out_size; (void)ws_size;

  // workspace carve (fp32 region first, then u16 region) — ~308 MB total
  float* wsf = (float*)d_ws;
  float* ssum    = wsf;                         // N*128
  float* wVnum   = wsf + (long)NN*128;          // N*128
  float* statacc = wsf + (long)2*NN*128;        // 1024
  float* statfin = statacc + 1024;              // 1024
  unsigned short* wsu   = (unsigned short*)(statfin + 1024);
  unsigned short* Wswz  = wsu;                  // 229376 swizzled bf16 weights
  unsigned short* Qbf   = Wswz + 229376;        // N*128
  unsigned short* Kbf   = Qbf + (long)NN*128;
  unsigned short* Vbf   = Kbf + (long)NN*128;
  unsigned short* h1pre = Vbf + (long)NN*128;   // N*128
  unsigned short* e1pre = h1pre + (long)NN*128; // E*128

  float* outF = (float*)d_out;
  float* outH = outF;
  float* outE = outF + (long)NN*128;

  k_zero<<<50004, 256, 0, stream>>>(wsf, (long)2*NN*128 + 1024);
  k_swizzle<<<896, 256, 0, stream>>>(Wq,Wk,Wv,We,Ohw,Oew,f1hw,f2hw,f1ew,f2ew, Wswz);
  k_qkv<<<dim3(782,3), 256, 0, stream>>>(h, Wswz, Qbf, Kbf, Vbf);
  k_score_e1<<<12500, 256, 0, stream>>>(e, srcI, dstI, Qbf, Kbf, Vbf,
                Wswz + 49152 /*We*/, Wswz + 81920 /*Oe*/, Oeb,
                ssum, wVnum, e1pre, statacc);
  k_h1<<<782, 256, 0, stream>>>(h, ssum, wVnum, Wswz + 65536 /*Oh*/, Ohb, h1pre, statacc);
  k_bnfin<<<1, 256, 0, stream>>>(statacc, statfin, g1h, b1h, g1e, b1e, (float)NN, (float)NE);
  k_ffn<<<782, 256, 0, stream>>>(h1pre, NN, Wswz+98304, f1hb, Wswz+131072, f2hb,
                statfin, statfin+128, outH, statacc+512, statacc+640);
  k_ffn<<<12500, 256, 0, stream>>>(e1pre, NE, Wswz+163840, f1eb, Wswz+196608, f2eb,
                statfin+256, statfin+384, outE, statacc+768, statacc+896);
  k_bnfin<<<1, 256, 0, stream>>>(statacc+512, statfin+512, g2h, b2h, g2e, b2e, (float)NN, (float)NE);
  k_final<<<106250, 256, 0, stream>>>(outF, statfin);
}